// Round 4
// baseline (345.594 us; speedup 1.0000x reference)
//
#include <hip/hip_runtime.h>

typedef __attribute__((ext_vector_type(8))) short short8;
typedef __attribute__((ext_vector_type(4))) float f32x4;

#define HW 65536
#define NPOS 32768

__device__ __forceinline__ unsigned short f2bf(float f) {
  unsigned u = __builtin_bit_cast(unsigned, f);
  u += 0x7fffu + ((u >> 16) & 1u);
  return (unsigned short)(u >> 16);
}
__device__ __forceinline__ float bf2f(unsigned short h) {
  unsigned u = (unsigned)h << 16;
  return __builtin_bit_cast(float, u);
}
__device__ __forceinline__ int slot3(int r) { return (r ^ (r >> 3)) & 7; }
__device__ __forceinline__ int slot4(int r) { return (r ^ (r >> 2)) & 15; }

// ---------------------------------------------------------------------------
// k0: split conv weights to bf16 hi/lo; rows 0-31 = phi, 32-63 = g.
// ---------------------------------------------------------------------------
__global__ __launch_bounds__(256) void k0_prep(
    const float* __restrict__ wphi, const float* __restrict__ wg,
    unsigned short* __restrict__ Whi, unsigned short* __restrict__ Wlo)
{
  const int idx = blockIdx.x * 256 + threadIdx.x;  // 4096 total
  const int u = idx >> 6, c = idx & 63;
  const float w = (u < 32) ? wphi[u * 64 + c] : wg[(u - 32) * 64 + c];
  const unsigned short h = f2bf(w);
  Whi[idx] = h;
  Wlo[idx] = f2bf(w - bf2f(h));
}

// ---------------------------------------------------------------------------
// k1: phi/g conv (MFMA; W split hi/lo, x single bf16) + exp + att (MFMA,
// single bf16 E) + sums. Grid (128, 8). 512 thr = 8 waves.
// LDS 32 KB -> 4 blocks/CU (100% wave occupancy).
// ---------------------------------------------------------------------------
__global__ __launch_bounds__(512, 8) void k1_att(
    const float* __restrict__ x, const unsigned short* __restrict__ Whi,
    const unsigned short* __restrict__ Wlo, float* __restrict__ attP,
    float* __restrict__ sums)
{
  __shared__ unsigned short xhs[128 * 64];   // [q][c] bf16, c XOR-swizzled by slot3(q)
  __shared__ unsigned short E[2][64 * 64];   // Ep, Eg  [c'][n], n swizzled by slot3(c')

  const int tid = threadIdx.x;
  const int b = blockIdx.y, blk = blockIdx.x;
  const int n0 = blk * 256;
  const int w = tid >> 6, l = tid & 63;
  const int lr = l & 15, g = l >> 4;
  const int ct = w & 3, hw4 = w >> 2;
  const int cti = w >> 1;
  const float* xb = x + (size_t)b * 64 * HW;

  // conv A-fragments (weights, split hi/lo)
  short8 wh[2], wl[2];
  #pragma unroll
  for (int ks = 0; ks < 2; ++ks) {
    const size_t off = (size_t)(ct * 16 + lr) * 64 + ks * 32 + g * 8;
    wh[ks] = *(const short8*)(Whi + off);
    wl[ks] = *(const short8*)(Wlo + off);
  }

  f32x4 aacc[2] = {{0.f, 0.f, 0.f, 0.f}, {0.f, 0.f, 0.f, 0.f}};
  float ssum = 0.f;

  // prologue: register-load sub-tile 0
  float4 xr[4];
  #pragma unroll
  for (int it = 0; it < 4; ++it) {
    const int c = (tid >> 4) + (it & 1) * 32;
    xr[it] = *(const float4*)(xb + (size_t)c * HW + (it >> 1) * NPOS + n0 + (tid & 15) * 4);
  }

  for (int t = 0; t < 4; ++t) {
    // convert + write x tile (transposed [q][c], single bf16)
    #pragma unroll
    for (int it = 0; it < 4; ++it) {
      const int c = (tid >> 4) + (it & 1) * 32;
      #pragma unroll
      for (int j = 0; j < 4; ++j) {
        const float f = ((const float*)&xr[it])[j];
        const int q = (it >> 1) * 64 + (tid & 15) * 4 + j;
        xhs[q * 64 + (c ^ (slot3(q) << 3))] = f2bf(f);
      }
    }
    __syncthreads();  // bar1: x tile ready; prev att done everywhere

    // prefetch next sub-tile into regs (overlaps conv/att below)
    if (t < 3) {
      const int n0s = n0 + (t + 1) * 64;
      #pragma unroll
      for (int it = 0; it < 4; ++it) {
        const int c = (tid >> 4) + (it & 1) * 32;
        xr[it] = *(const float4*)(xb + (size_t)c * HW + (it >> 1) * NPOS + n0s + (tid & 15) * 4);
      }
    }

    // conv: 4 pos-tiles, K=64, 2-product split (Wh*x + Wl*x)
    f32x4 cacc[4] = {{0.f,0.f,0.f,0.f},{0.f,0.f,0.f,0.f},{0.f,0.f,0.f,0.f},{0.f,0.f,0.f,0.f}};
    #pragma unroll
    for (int pti = 0; pti < 4; ++pti) {
      const int q = (hw4 * 4 + pti) * 16 + lr;
      const int sw = slot3(q) << 3;
      #pragma unroll
      for (int ks = 0; ks < 2; ++ks) {
        const short8 bxh = *(const short8*)&xhs[q * 64 + ((ks * 32 + g * 8) ^ sw)];
        cacc[pti] = __builtin_amdgcn_mfma_f32_16x16x32_bf16(wh[ks], bxh, cacc[pti], 0, 0, 0);
        cacc[pti] = __builtin_amdgcn_mfma_f32_16x16x32_bf16(wl[ks], bxh, cacc[pti], 0, 0, 0);
      }
    }

    // exp + E write (view rows c' = 2i + h, single bf16)
    {
      unsigned short* EH = (ct < 2) ? E[0] : E[1];
      #pragma unroll
      for (int pti = 0; pti < 4; ++pti) {
        const int n = pti * 16 + lr;
        #pragma unroll
        for (int r = 0; r < 4; ++r) {
          const float e = __expf(cacc[pti][r]);
          ssum += e;
          const int cp = 2 * ((ct & 1) * 16 + g * 4 + r) + hw4;
          EH[cp * 64 + (n ^ (slot3(cp) << 3))] = f2bf(e);
        }
      }
    }
    __syncthreads();  // bar2: E ready

    // att partial: att[c'][d'] += sum_n Eg[c'][n] * Ep[d'][n]
    #pragma unroll
    for (int ks = 0; ks < 2; ++ks) {
      const int ar = cti * 16 + lr;
      const short8 agh = *(const short8*)&E[1][ar * 64 + ((ks * 32 + g * 8) ^ (slot3(ar) << 3))];
      #pragma unroll
      for (int j = 0; j < 2; ++j) {
        const int dr = ((w & 1) * 2 + j) * 16 + lr;
        const short8 bph = *(const short8*)&E[0][dr * 64 + ((ks * 32 + g * 8) ^ (slot3(dr) << 3))];
        aacc[j] = __builtin_amdgcn_mfma_f32_16x16x32_bf16(agh, bph, aacc[j], 0, 0, 0);
      }
    }
  }

  // flush att partials (contention-free: per-block buffer)
  float* ap = attP + ((size_t)(b * 128 + blk)) * 4096;
  #pragma unroll
  for (int j = 0; j < 2; ++j)
    #pragma unroll
    for (int r = 0; r < 4; ++r)
      ap[(cti * 16 + g * 4 + r) * 64 + ((w & 1) * 2 + j) * 16 + lr] = aacc[j][r];

  // softmax denominators
  #pragma unroll
  for (int off = 32; off > 0; off >>= 1) ssum += __shfl_down(ssum, off);
  if (l == 0) atomicAdd(&sums[(ct < 2 ? 0 : 8) + b], ssum);
}

// ---------------------------------------------------------------------------
// k3: reduce att partials; N[b][oo=h*64+o][cc=e*64+c] =
//     scale * sum_j ( sum_i wm[o][i]*att[2i+h][2j+e] ) * Wth[j][c]  -> bf16 hi/lo
// ---------------------------------------------------------------------------
__global__ __launch_bounds__(1024) void k3_nmat(
    const float* __restrict__ attP, const float* __restrict__ sums,
    const float* __restrict__ wm, const float* __restrict__ wtheta,
    unsigned short* __restrict__ Nhi, unsigned short* __restrict__ Nlo)
{
  __shared__ float att_s[4096];
  __shared__ float Mp[2][64][64];
  __shared__ float wms[64][32];
  __shared__ float wts[32][64];
  const int tid = threadIdx.x;
  const int b = blockIdx.x;

  if (tid < 512) {
    if (tid < 256) { for (int k = tid; k < 2048; k += 256) wms[k >> 5][k & 31] = wm[k]; }
    else           { for (int k = tid - 256; k < 2048; k += 256) wts[k >> 6][k & 63] = wtheta[k]; }
  }
  for (int e = tid; e < 4096; e += 1024) {
    const float* p = attP + (size_t)b * 128 * 4096 + e;
    float s0 = 0.f, s1 = 0.f, s2 = 0.f, s3 = 0.f;
    for (int q = 0; q < 128; q += 4) {
      s0 += p[(size_t)q * 4096];
      s1 += p[(size_t)(q + 1) * 4096];
      s2 += p[(size_t)(q + 2) * 4096];
      s3 += p[(size_t)(q + 3) * 4096];
    }
    att_s[e] = (s0 + s1) + (s2 + s3);
  }
  __syncthreads();
  for (int idx = tid; idx < 8192; idx += 1024) {
    const int h = idx >> 12, o = (idx >> 6) & 63, d = idx & 63;
    float s = 0.f;
    #pragma unroll
    for (int i = 0; i < 32; ++i)
      s = __builtin_fmaf(wms[o][i], att_s[(2 * i + h) * 64 + d], s);
    Mp[h][o][d] = s;
  }
  __syncthreads();
  const float scale = 1.f / (sums[b] * sums[8 + b]);
  for (int idx = tid; idx < 16384; idx += 1024) {
    const int oo = idx >> 7, cc = idx & 127;
    const int h = oo >> 6, o = oo & 63, e = cc >> 6, c = cc & 63;
    float s = 0.f;
    #pragma unroll
    for (int j = 0; j < 32; ++j)
      s = __builtin_fmaf(Mp[h][o][2 * j + e], wts[j][c], s);
    s *= scale;
    const unsigned short hi = f2bf(s);
    Nhi[(size_t)b * 16384 + idx] = hi;
    Nlo[(size_t)b * 16384 + idx] = f2bf(s - bf2f(hi));
  }
}

// ---------------------------------------------------------------------------
// k5: out[b][o][h*NPOS+n] = sum_cc N[b][h*64+o][cc] * x[b][cc&63][(cc>>6)*NPOS+n]
// Grid (512, 8). N split hi/lo (A-side), x single bf16. LDS 16 KB.
// ---------------------------------------------------------------------------
__global__ __launch_bounds__(512, 8) void k5_out(
    const float* __restrict__ x, const unsigned short* __restrict__ Nhi,
    const unsigned short* __restrict__ Nlo, float* __restrict__ out)
{
  __shared__ unsigned short Xh[64 * 128];   // [n][cc] bf16, slot4-swizzled
  const int tid = threadIdx.x;
  const int b = blockIdx.y, n0 = blockIdx.x * 64;
  const int w = tid >> 6, l = tid & 63;
  const int lr = l & 15, g = l >> 4;
  const float* xb = x + (size_t)b * 64 * HW;

  // A-fragments: N rows 16w..16w+15, K=128 (4 ksteps), hi/lo
  short8 ah[4], al[4];
  #pragma unroll
  for (int ks = 0; ks < 4; ++ks) {
    const size_t off = (size_t)b * 16384 + (size_t)(w * 16 + lr) * 128 + ks * 32 + g * 8;
    ah[ks] = *(const short8*)(Nhi + off);
    al[ks] = *(const short8*)(Nlo + off);
  }

  // stage X tile transposed: [n][cc], single bf16
  #pragma unroll
  for (int it = 0; it < 4; ++it) {
    const int cc = (tid >> 4) + it * 32;
    const int c = cc & 63, e = cc >> 6;
    const float4 v = *(const float4*)(xb + (size_t)c * HW + e * NPOS + n0 + (tid & 15) * 4);
    #pragma unroll
    for (int j = 0; j < 4; ++j) {
      const int n = (tid & 15) * 4 + j;
      Xh[n * 128 + (cc ^ (slot4(n) << 3))] = f2bf(((const float*)&v)[j]);
    }
  }
  __syncthreads();

  const int hh = w >> 2;                    // output half (oo>>6)
  const int obase = (w & 3) * 16 + g * 4;   // o = obase + r
  float* ob = out + (size_t)b * 64 * HW + (size_t)hh * NPOS;

  #pragma unroll
  for (int ct4 = 0; ct4 < 4; ++ct4) {
    f32x4 acc = {0.f, 0.f, 0.f, 0.f};
    const int row = ct4 * 16 + lr;
    const int sw = slot4(row) << 3;
    #pragma unroll
    for (int ks = 0; ks < 4; ++ks) {
      const short8 bh = *(const short8*)&Xh[row * 128 + ((ks * 32 + g * 8) ^ sw)];
      acc = __builtin_amdgcn_mfma_f32_16x16x32_bf16(ah[ks], bh, acc, 0, 0, 0);
      acc = __builtin_amdgcn_mfma_f32_16x16x32_bf16(al[ks], bh, acc, 0, 0, 0);
    }
    const int n = n0 + ct4 * 16 + lr;
    #pragma unroll
    for (int r = 0; r < 4; ++r)
      ob[(size_t)(obase + r) * HW + n] = acc[r];
  }
}

// ---------------------------------------------------------------------------
extern "C" void kernel_launch(void* const* d_in, const int* in_sizes, int n_in,
                              void* d_out, int out_size, void* d_ws, size_t ws_size,
                              hipStream_t stream)
{
  const float* x      = (const float*)d_in[0];
  const float* wphi   = (const float*)d_in[1];
  const float* wtheta = (const float*)d_in[2];
  const float* wg     = (const float*)d_in[3];
  const float* wm     = (const float*)d_in[4];
  float* out = (float*)d_out;

  char* ws = (char*)d_ws;
  float* attP         = (float*)ws;                                 // 16,777,216 B
  unsigned short* Whi = (unsigned short*)(ws + 16777216);           //      8,192 B
  unsigned short* Wlo = (unsigned short*)(ws + 16785408);           //      8,192 B
  unsigned short* Nhi = (unsigned short*)(ws + 16793600);           //    262,144 B
  unsigned short* Nlo = (unsigned short*)(ws + 17055744);           //    262,144 B
  float* sums         = (float*)(ws + 17317888);                    //         64 B

  hipMemsetAsync(sums, 0, 64, stream);
  k0_prep<<<dim3(16), 256, 0, stream>>>(wphi, wg, Whi, Wlo);
  k1_att<<<dim3(128, 8), 512, 0, stream>>>(x, Whi, Wlo, attP, sums);
  k3_nmat<<<dim3(8), 1024, 0, stream>>>(attP, sums, wm, wtheta, Nhi, Nlo);
  k5_out<<<dim3(512, 8), 512, 0, stream>>>(x, Nhi, Nlo, out);
}

// Round 5
// 276.699 us; speedup vs baseline: 1.2490x; 1.2490x over previous
//
#include <hip/hip_runtime.h>

typedef __attribute__((ext_vector_type(8))) short short8;
typedef __attribute__((ext_vector_type(4))) float f32x4;

#define HW 65536
#define NPOS 32768

__device__ __forceinline__ unsigned short f2bf(float f) {
  unsigned u = __builtin_bit_cast(unsigned, f);
  u += 0x7fffu + ((u >> 16) & 1u);
  return (unsigned short)(u >> 16);
}
__device__ __forceinline__ float bf2f(unsigned short h) {
  unsigned u = (unsigned)h << 16;
  return __builtin_bit_cast(float, u);
}
__device__ __forceinline__ int slot3(int r) { return (r ^ (r >> 3)) & 7; }
__device__ __forceinline__ int slot4(int r) { return (r ^ (r >> 2)) & 15; }

// ---------------------------------------------------------------------------
// k0: split conv weights to bf16 hi/lo; rows 0-31 = phi, 32-63 = g.
// ---------------------------------------------------------------------------
__global__ __launch_bounds__(256) void k0_prep(
    const float* __restrict__ wphi, const float* __restrict__ wg,
    unsigned short* __restrict__ Whi, unsigned short* __restrict__ Wlo)
{
  const int idx = blockIdx.x * 256 + threadIdx.x;  // 4096 total
  const int u = idx >> 6, c = idx & 63;
  const float w = (u < 32) ? wphi[u * 64 + c] : wg[(u - 32) * 64 + c];
  const unsigned short h = f2bf(w);
  Whi[idx] = h;
  Wlo[idx] = f2bf(w - bf2f(h));
}

// ---------------------------------------------------------------------------
// k1: phi/g conv (MFMA; W split hi/lo, x single bf16) + exp + att (MFMA,
// single bf16 E) + sums. Grid (128, 8). 512 thr = 8 waves.
// LDS 32 KB; (512,6): ~85 VGPR budget (kernel needs ~75, no spill),
// 3 blocks/CU = 24 waves/CU.
// ---------------------------------------------------------------------------
__global__ __launch_bounds__(512, 6) void k1_att(
    const float* __restrict__ x, const unsigned short* __restrict__ Whi,
    const unsigned short* __restrict__ Wlo, float* __restrict__ attP,
    float* __restrict__ sums)
{
  __shared__ unsigned short xhs[128 * 64];   // [q][c] bf16, c XOR-swizzled by slot3(q)
  __shared__ unsigned short E[2][64 * 64];   // Ep, Eg  [c'][n], n swizzled by slot3(c')

  const int tid = threadIdx.x;
  const int b = blockIdx.y, blk = blockIdx.x;
  const int n0 = blk * 256;
  const int w = tid >> 6, l = tid & 63;
  const int lr = l & 15, g = l >> 4;
  const int ct = w & 3, hw4 = w >> 2;
  const int cti = w >> 1;
  const float* xb = x + (size_t)b * 64 * HW;

  // conv A-fragments (weights, split hi/lo)
  short8 wh[2], wl[2];
  #pragma unroll
  for (int ks = 0; ks < 2; ++ks) {
    const size_t off = (size_t)(ct * 16 + lr) * 64 + ks * 32 + g * 8;
    wh[ks] = *(const short8*)(Whi + off);
    wl[ks] = *(const short8*)(Wlo + off);
  }

  f32x4 aacc[2] = {{0.f, 0.f, 0.f, 0.f}, {0.f, 0.f, 0.f, 0.f}};
  float ssum = 0.f;

  // prologue: register-load sub-tile 0
  float4 xr[4];
  #pragma unroll
  for (int it = 0; it < 4; ++it) {
    const int c = (tid >> 4) + (it & 1) * 32;
    xr[it] = *(const float4*)(xb + (size_t)c * HW + (it >> 1) * NPOS + n0 + (tid & 15) * 4);
  }

  for (int t = 0; t < 4; ++t) {
    // convert + write x tile (transposed [q][c], single bf16)
    #pragma unroll
    for (int it = 0; it < 4; ++it) {
      const int c = (tid >> 4) + (it & 1) * 32;
      #pragma unroll
      for (int j = 0; j < 4; ++j) {
        const float f = ((const float*)&xr[it])[j];
        const int q = (it >> 1) * 64 + (tid & 15) * 4 + j;
        xhs[q * 64 + (c ^ (slot3(q) << 3))] = f2bf(f);
      }
    }
    __syncthreads();  // bar1: x tile ready; prev att done everywhere

    // prefetch next sub-tile into regs (overlaps conv/att below)
    if (t < 3) {
      const int n0s = n0 + (t + 1) * 64;
      #pragma unroll
      for (int it = 0; it < 4; ++it) {
        const int c = (tid >> 4) + (it & 1) * 32;
        xr[it] = *(const float4*)(xb + (size_t)c * HW + (it >> 1) * NPOS + n0s + (tid & 15) * 4);
      }
    }

    // conv: 4 pos-tiles, K=64, 2-product split (Wh*x + Wl*x)
    f32x4 cacc[4] = {{0.f,0.f,0.f,0.f},{0.f,0.f,0.f,0.f},{0.f,0.f,0.f,0.f},{0.f,0.f,0.f,0.f}};
    #pragma unroll
    for (int pti = 0; pti < 4; ++pti) {
      const int q = (hw4 * 4 + pti) * 16 + lr;
      const int sw = slot3(q) << 3;
      #pragma unroll
      for (int ks = 0; ks < 2; ++ks) {
        const short8 bxh = *(const short8*)&xhs[q * 64 + ((ks * 32 + g * 8) ^ sw)];
        cacc[pti] = __builtin_amdgcn_mfma_f32_16x16x32_bf16(wh[ks], bxh, cacc[pti], 0, 0, 0);
        cacc[pti] = __builtin_amdgcn_mfma_f32_16x16x32_bf16(wl[ks], bxh, cacc[pti], 0, 0, 0);
      }
    }

    // exp + E write (view rows c' = 2i + h, single bf16)
    {
      unsigned short* EH = (ct < 2) ? E[0] : E[1];
      #pragma unroll
      for (int pti = 0; pti < 4; ++pti) {
        const int n = pti * 16 + lr;
        #pragma unroll
        for (int r = 0; r < 4; ++r) {
          const float e = __expf(cacc[pti][r]);
          ssum += e;
          const int cp = 2 * ((ct & 1) * 16 + g * 4 + r) + hw4;
          EH[cp * 64 + (n ^ (slot3(cp) << 3))] = f2bf(e);
        }
      }
    }
    __syncthreads();  // bar2: E ready

    // att partial: att[c'][d'] += sum_n Eg[c'][n] * Ep[d'][n]
    #pragma unroll
    for (int ks = 0; ks < 2; ++ks) {
      const int ar = cti * 16 + lr;
      const short8 agh = *(const short8*)&E[1][ar * 64 + ((ks * 32 + g * 8) ^ (slot3(ar) << 3))];
      #pragma unroll
      for (int j = 0; j < 2; ++j) {
        const int dr = ((w & 1) * 2 + j) * 16 + lr;
        const short8 bph = *(const short8*)&E[0][dr * 64 + ((ks * 32 + g * 8) ^ (slot3(dr) << 3))];
        aacc[j] = __builtin_amdgcn_mfma_f32_16x16x32_bf16(agh, bph, aacc[j], 0, 0, 0);
      }
    }
  }

  // flush att partials (contention-free: per-block buffer)
  float* ap = attP + ((size_t)(b * 128 + blk)) * 4096;
  #pragma unroll
  for (int j = 0; j < 2; ++j)
    #pragma unroll
    for (int r = 0; r < 4; ++r)
      ap[(cti * 16 + g * 4 + r) * 64 + ((w & 1) * 2 + j) * 16 + lr] = aacc[j][r];

  // softmax denominators
  #pragma unroll
  for (int off = 32; off > 0; off >>= 1) ssum += __shfl_down(ssum, off);
  if (l == 0) atomicAdd(&sums[(ct < 2 ? 0 : 8) + b], ssum);
}

// ---------------------------------------------------------------------------
// k3a: partial-reduce att partials 128 -> 8 per batch. Grid (64).
// ---------------------------------------------------------------------------
__global__ __launch_bounds__(256) void k3a_reduce(
    const float* __restrict__ attP, float* __restrict__ attQ)
{
  const int b = blockIdx.x >> 3, part = blockIdx.x & 7;
  const float* p = attP + (size_t)(b * 128 + part * 16) * 4096;
  float* q = attQ + (size_t)(b * 8 + part) * 4096;
  for (int e = threadIdx.x; e < 4096; e += 256) {
    float s0 = 0.f, s1 = 0.f, s2 = 0.f, s3 = 0.f;
    #pragma unroll
    for (int k = 0; k < 16; k += 4) {
      s0 += p[(size_t)k * 4096 + e];
      s1 += p[(size_t)(k + 1) * 4096 + e];
      s2 += p[(size_t)(k + 2) * 4096 + e];
      s3 += p[(size_t)(k + 3) * 4096 + e];
    }
    q[e] = (s0 + s1) + (s2 + s3);
  }
}

// ---------------------------------------------------------------------------
// k3b: final reduce + N[b][oo=h*64+o][cc=e*64+c] =
//      scale * sum_j ( sum_i wm[o][i]*att[2i+h][2j+e] ) * Wth[j][c] -> bf16 hi/lo
// ---------------------------------------------------------------------------
__global__ __launch_bounds__(1024) void k3b_nmat(
    const float* __restrict__ attQ, const float* __restrict__ sums,
    const float* __restrict__ wm, const float* __restrict__ wtheta,
    unsigned short* __restrict__ Nhi, unsigned short* __restrict__ Nlo)
{
  __shared__ float att_s[4096];
  __shared__ float Mp[2][64][64];
  __shared__ float wms[64][32];
  __shared__ float wts[32][64];
  const int tid = threadIdx.x;
  const int b = blockIdx.x;

  if (tid < 512) {
    if (tid < 256) { for (int k = tid; k < 2048; k += 256) wms[k >> 5][k & 31] = wm[k]; }
    else           { for (int k = tid - 256; k < 2048; k += 256) wts[k >> 6][k & 63] = wtheta[k]; }
  }
  for (int e = tid; e < 4096; e += 1024) {
    const float* p = attQ + (size_t)b * 8 * 4096 + e;
    float s = 0.f;
    #pragma unroll
    for (int q = 0; q < 8; ++q) s += p[(size_t)q * 4096];
    att_s[e] = s;
  }
  __syncthreads();
  for (int idx = tid; idx < 8192; idx += 1024) {
    const int h = idx >> 12, o = (idx >> 6) & 63, d = idx & 63;
    float s = 0.f;
    #pragma unroll
    for (int i = 0; i < 32; ++i)
      s = __builtin_fmaf(wms[o][i], att_s[(2 * i + h) * 64 + d], s);
    Mp[h][o][d] = s;
  }
  __syncthreads();
  const float scale = 1.f / (sums[b] * sums[8 + b]);
  for (int idx = tid; idx < 16384; idx += 1024) {
    const int oo = idx >> 7, cc = idx & 127;
    const int h = oo >> 6, o = oo & 63, e = cc >> 6, c = cc & 63;
    float s = 0.f;
    #pragma unroll
    for (int j = 0; j < 32; ++j)
      s = __builtin_fmaf(Mp[h][o][2 * j + e], wts[j][c], s);
    s *= scale;
    const unsigned short hi = f2bf(s);
    Nhi[(size_t)b * 16384 + idx] = hi;
    Nlo[(size_t)b * 16384 + idx] = f2bf(s - bf2f(hi));
  }
}

// ---------------------------------------------------------------------------
// k5: out[b][o][h*NPOS+n] = sum_cc N[b][h*64+o][cc] * x[b][cc&63][(cc>>6)*NPOS+n]
// Swapped operands: A = x rows (n), B = N rows (oo)  ->  D row = n ->
// each lane stores float4 (4 consecutive n). Grid (512, 8), LDS 16 KB.
// ---------------------------------------------------------------------------
__global__ __launch_bounds__(512, 6) void k5_out(
    const float* __restrict__ x, const unsigned short* __restrict__ Nhi,
    const unsigned short* __restrict__ Nlo, float* __restrict__ out)
{
  __shared__ unsigned short Xh[64 * 128];   // [n][cc] bf16, slot4-swizzled
  const int tid = threadIdx.x;
  const int b = blockIdx.y, n0 = blockIdx.x * 64;
  const int w = tid >> 6, l = tid & 63;
  const int lr = l & 15, g = l >> 4;
  const float* xb = x + (size_t)b * 64 * HW;

  // B-fragments: N rows oo = w*16 + lr, K=128 (4 ksteps), hi/lo
  short8 bh[4], bl[4];
  #pragma unroll
  for (int ks = 0; ks < 4; ++ks) {
    const size_t off = (size_t)b * 16384 + (size_t)(w * 16 + lr) * 128 + ks * 32 + g * 8;
    bh[ks] = *(const short8*)(Nhi + off);
    bl[ks] = *(const short8*)(Nlo + off);
  }

  // stage X tile transposed: [n][cc], single bf16
  #pragma unroll
  for (int it = 0; it < 4; ++it) {
    const int cc = (tid >> 4) + it * 32;
    const int c = cc & 63, e = cc >> 6;
    const float4 v = *(const float4*)(xb + (size_t)c * HW + e * NPOS + n0 + (tid & 15) * 4);
    #pragma unroll
    for (int j = 0; j < 4; ++j) {
      const int n = (tid & 15) * 4 + j;
      Xh[n * 128 + (cc ^ (slot4(n) << 3))] = f2bf(((const float*)&v)[j]);
    }
  }
  __syncthreads();

  const int oo = w * 16 + lr;   // this lane's output row (D col = lr)
  float* op = out + (size_t)b * 64 * HW + (size_t)(oo & 63) * HW
            + (size_t)(oo >> 6) * NPOS + n0 + g * 4;

  #pragma unroll
  for (int ct4 = 0; ct4 < 4; ++ct4) {
    f32x4 acc = {0.f, 0.f, 0.f, 0.f};
    const int arow = ct4 * 16 + lr;
    const int sw = slot4(arow) << 3;
    #pragma unroll
    for (int ks = 0; ks < 4; ++ks) {
      const short8 av = *(const short8*)&Xh[arow * 128 + ((ks * 32 + g * 8) ^ sw)];
      acc = __builtin_amdgcn_mfma_f32_16x16x32_bf16(av, bh[ks], acc, 0, 0, 0);
      acc = __builtin_amdgcn_mfma_f32_16x16x32_bf16(av, bl[ks], acc, 0, 0, 0);
    }
    // D: row (n within subtile) = g*4 + r, col = lr -> float4 store
    *(float4*)(op + ct4 * 16) = *(float4*)&acc;
  }
}

// ---------------------------------------------------------------------------
extern "C" void kernel_launch(void* const* d_in, const int* in_sizes, int n_in,
                              void* d_out, int out_size, void* d_ws, size_t ws_size,
                              hipStream_t stream)
{
  const float* x      = (const float*)d_in[0];
  const float* wphi   = (const float*)d_in[1];
  const float* wtheta = (const float*)d_in[2];
  const float* wg     = (const float*)d_in[3];
  const float* wm     = (const float*)d_in[4];
  float* out = (float*)d_out;

  char* ws = (char*)d_ws;
  float* attP         = (float*)ws;                                 // 16,777,216 B
  unsigned short* Whi = (unsigned short*)(ws + 16777216);           //      8,192 B
  unsigned short* Wlo = (unsigned short*)(ws + 16785408);           //      8,192 B
  unsigned short* Nhi = (unsigned short*)(ws + 16793600);           //    262,144 B
  unsigned short* Nlo = (unsigned short*)(ws + 17055744);           //    262,144 B
  float* sums         = (float*)(ws + 17317888);                    //         64 B
  float* attQ         = (float*)(ws + 17317952);                    //  1,048,576 B

  hipMemsetAsync(sums, 0, 64, stream);
  k0_prep<<<dim3(16), 256, 0, stream>>>(wphi, wg, Whi, Wlo);
  k1_att<<<dim3(128, 8), 512, 0, stream>>>(x, Whi, Wlo, attP, sums);
  k3a_reduce<<<dim3(64), 256, 0, stream>>>(attP, attQ);
  k3b_nmat<<<dim3(8), 1024, 0, stream>>>(attQ, sums, wm, wtheta, Nhi, Nlo);
  k5_out<<<dim3(512, 8), 512, 0, stream>>>(x, Nhi, Nlo, out);
}

// Round 6
// 213.784 us; speedup vs baseline: 1.6166x; 1.2943x over previous
//
#include <hip/hip_runtime.h>

typedef __attribute__((ext_vector_type(8))) short short8;
typedef __attribute__((ext_vector_type(4))) float f32x4;

#define HW 65536
#define NPOS 32768

__device__ __forceinline__ unsigned short f2bf(float f) {
  unsigned u = __builtin_bit_cast(unsigned, f);
  u += 0x7fffu + ((u >> 16) & 1u);
  return (unsigned short)(u >> 16);
}
__device__ __forceinline__ float bf2f(unsigned short h) {
  unsigned u = (unsigned)h << 16;
  return __builtin_bit_cast(float, u);
}
__device__ __forceinline__ int slot3(int r) { return (r ^ (r >> 3)) & 7; }
__device__ __forceinline__ int slot4(int r) { return (r ^ (r >> 2)) & 15; }

// ---------------------------------------------------------------------------
// k0: split conv weights to bf16 hi/lo; rows 0-31 = phi, 32-63 = g.
// ---------------------------------------------------------------------------
__global__ __launch_bounds__(256) void k0_prep(
    const float* __restrict__ wphi, const float* __restrict__ wg,
    unsigned short* __restrict__ Whi, unsigned short* __restrict__ Wlo)
{
  const int idx = blockIdx.x * 256 + threadIdx.x;  // 4096 total
  const int u = idx >> 6, c = idx & 63;
  const float w = (u < 32) ? wphi[u * 64 + c] : wg[(u - 32) * 64 + c];
  const unsigned short h = f2bf(w);
  Whi[idx] = h;
  Wlo[idx] = f2bf(w - bf2f(h));
}

// ---------------------------------------------------------------------------
// k1: phi/g conv (MFMA, A=x B=W) + exp + att (MFMA) + sums.
// Grid (128, 8), 512 thr = 8 waves. LDS 32 KB.
// __launch_bounds__(512,3): 3 blocks/CU (CUDA blocks-per-CU semantics!)
// -> 6 waves/SIMD -> 85 VGPR budget (kernel needs ~76, no spill).
// Staging: per-lane scalar dword loads (lanes span pos, coalesced) so each
// thread holds 16 contiguous channels at one pos -> 2x ds_write_b128.
// ---------------------------------------------------------------------------
__global__ __launch_bounds__(512, 3) void k1_att(
    const float* __restrict__ x, const unsigned short* __restrict__ Whi,
    const unsigned short* __restrict__ Wlo, float* __restrict__ attP,
    float* __restrict__ sums)
{
  __shared__ unsigned short xhs[128 * 64];   // [q][c] bf16, c ^ (slot3(q)<<3)
  __shared__ unsigned short E[2][64 * 64];   // Ep, Eg  [c'][n], n ^ (slot3(c')<<3)

  const int tid = threadIdx.x;
  const int b = blockIdx.y, blk = blockIdx.x;
  const int n0 = blk * 256;
  const int w = tid >> 6, l = tid & 63;
  const int lr = l & 15, g = l >> 4;
  const int ct = w & 3, hw4 = w >> 2;
  const int cti = w >> 1;

  // staging role: pos-half ph, channel group cbase (16 contiguous c)
  const int ph = w & 1, cbase = (w >> 1) * 16;
  const int q = ph * 64 + l;                 // this thread's LDS row (pos)
  const int s8q = slot3(q) << 3;
  const float* xp = x + (size_t)b * 64 * HW + (size_t)cbase * HW
                  + (size_t)ph * NPOS + n0 + l;

  // conv B-fragments (weights, split hi/lo); B col = ch = lr
  short8 wh[2], wl[2];
  #pragma unroll
  for (int ks = 0; ks < 2; ++ks) {
    const size_t off = (size_t)(ct * 16 + lr) * 64 + ks * 32 + g * 8;
    wh[ks] = *(const short8*)(Whi + off);
    wl[ks] = *(const short8*)(Wlo + off);
  }

  f32x4 aacc[2] = {{0.f, 0.f, 0.f, 0.f}, {0.f, 0.f, 0.f, 0.f}};
  float ssum = 0.f;

  // prologue: scalar-load sub-tile 0 (16 channels at this thread's pos)
  float xv[16];
  #pragma unroll
  for (int i = 0; i < 16; ++i) xv[i] = xp[(size_t)i * HW];

  for (int t = 0; t < 4; ++t) {
    // pack 16 contiguous channels -> 2 x ds_write_b128
    {
      short8 pa, pb;
      #pragma unroll
      for (int i = 0; i < 8; ++i) {
        pa[i] = (short)f2bf(xv[i]);
        pb[i] = (short)f2bf(xv[8 + i]);
      }
      *(short8*)&xhs[q * 64 + (cbase ^ s8q)] = pa;
      *(short8*)&xhs[q * 64 + ((cbase + 8) ^ s8q)] = pb;
    }
    __syncthreads();  // bar1: x tile ready (prev att finished before this)

    // prefetch next sub-tile (overlaps conv/att below)
    if (t < 3) {
      #pragma unroll
      for (int i = 0; i < 16; ++i) xv[i] = xp[(size_t)i * HW + (t + 1) * 64];
    }

    // conv: A = x [pos][c], B = W [c][ch] -> D[pos][ch]
    f32x4 cacc[4] = {{0.f,0.f,0.f,0.f},{0.f,0.f,0.f,0.f},{0.f,0.f,0.f,0.f},{0.f,0.f,0.f,0.f}};
    #pragma unroll
    for (int pti = 0; pti < 4; ++pti) {
      const int qa = (hw4 * 4 + pti) * 16 + lr;  // A row = pos
      const int sw = slot3(qa) << 3;
      #pragma unroll
      for (int ks = 0; ks < 2; ++ks) {
        const short8 av = *(const short8*)&xhs[qa * 64 + ((ks * 32 + g * 8) ^ sw)];
        cacc[pti] = __builtin_amdgcn_mfma_f32_16x16x32_bf16(av, wh[ks], cacc[pti], 0, 0, 0);
        cacc[pti] = __builtin_amdgcn_mfma_f32_16x16x32_bf16(av, wl[ks], cacc[pti], 0, 0, 0);
      }
    }

    // exp + E write: lane owns ch = ct*16+lr (fixed c'), 4 consecutive n per pti
    {
      unsigned short* EH = (ct < 2) ? E[0] : E[1];
      const int cp = 2 * ((ct & 1) * 16 + lr) + hw4;   // view row (fixed per lane)
      const int scp = slot3(cp) << 3;
      #pragma unroll
      for (int pti = 0; pti < 4; ++pti) {
        float e0 = __expf(cacc[pti][0]), e1 = __expf(cacc[pti][1]);
        float e2 = __expf(cacc[pti][2]), e3 = __expf(cacc[pti][3]);
        ssum += (e0 + e1) + (e2 + e3);
        uint2 pk;
        pk.x = (unsigned)f2bf(e0) | ((unsigned)f2bf(e1) << 16);
        pk.y = (unsigned)f2bf(e2) | ((unsigned)f2bf(e3) << 16);
        *(uint2*)&EH[cp * 64 + ((pti * 16 + g * 4) ^ scp)] = pk;
      }
    }
    __syncthreads();  // bar2: E ready

    // att partial: att[c'][d'] += sum_n Eg[c'][n] * Ep[d'][n]
    #pragma unroll
    for (int ks = 0; ks < 2; ++ks) {
      const int ar = cti * 16 + lr;
      const short8 agh = *(const short8*)&E[1][ar * 64 + ((ks * 32 + g * 8) ^ (slot3(ar) << 3))];
      #pragma unroll
      for (int j = 0; j < 2; ++j) {
        const int dr = ((w & 1) * 2 + j) * 16 + lr;
        const short8 bph = *(const short8*)&E[0][dr * 64 + ((ks * 32 + g * 8) ^ (slot3(dr) << 3))];
        aacc[j] = __builtin_amdgcn_mfma_f32_16x16x32_bf16(agh, bph, aacc[j], 0, 0, 0);
      }
    }
  }

  // flush att partials (contention-free: per-block buffer)
  float* ap = attP + ((size_t)(b * 128 + blk)) * 4096;
  #pragma unroll
  for (int j = 0; j < 2; ++j)
    #pragma unroll
    for (int r = 0; r < 4; ++r)
      ap[(cti * 16 + g * 4 + r) * 64 + ((w & 1) * 2 + j) * 16 + lr] = aacc[j][r];

  // softmax denominators
  #pragma unroll
  for (int off = 32; off > 0; off >>= 1) ssum += __shfl_down(ssum, off);
  if (l == 0) atomicAdd(&sums[(ct < 2 ? 0 : 8) + b], ssum);
}

// ---------------------------------------------------------------------------
// k3a: partial-reduce att partials 128 -> 8 per batch. Grid (64).
// ---------------------------------------------------------------------------
__global__ __launch_bounds__(256) void k3a_reduce(
    const float* __restrict__ attP, float* __restrict__ attQ)
{
  const int b = blockIdx.x >> 3, part = blockIdx.x & 7;
  const float* p = attP + (size_t)(b * 128 + part * 16) * 4096;
  float* q = attQ + (size_t)(b * 8 + part) * 4096;
  for (int e = threadIdx.x; e < 4096; e += 256) {
    float s0 = 0.f, s1 = 0.f, s2 = 0.f, s3 = 0.f;
    #pragma unroll
    for (int k = 0; k < 16; k += 4) {
      s0 += p[(size_t)k * 4096 + e];
      s1 += p[(size_t)(k + 1) * 4096 + e];
      s2 += p[(size_t)(k + 2) * 4096 + e];
      s3 += p[(size_t)(k + 3) * 4096 + e];
    }
    q[e] = (s0 + s1) + (s2 + s3);
  }
}

// ---------------------------------------------------------------------------
// k3b: final reduce + N[b][oo=h*64+o][cc=e*64+c] =
//      scale * sum_j ( sum_i wm[o][i]*att[2i+h][2j+e] ) * Wth[j][c] -> bf16 hi/lo
// ---------------------------------------------------------------------------
__global__ __launch_bounds__(1024) void k3b_nmat(
    const float* __restrict__ attQ, const float* __restrict__ sums,
    const float* __restrict__ wm, const float* __restrict__ wtheta,
    unsigned short* __restrict__ Nhi, unsigned short* __restrict__ Nlo)
{
  __shared__ float att_s[4096];
  __shared__ float Mp[2][64][64];
  __shared__ float wms[64][32];
  __shared__ float wts[32][64];
  const int tid = threadIdx.x;
  const int b = blockIdx.x;

  if (tid < 512) {
    if (tid < 256) { for (int k = tid; k < 2048; k += 256) wms[k >> 5][k & 31] = wm[k]; }
    else           { for (int k = tid - 256; k < 2048; k += 256) wts[k >> 6][k & 63] = wtheta[k]; }
  }
  for (int e = tid; e < 4096; e += 1024) {
    const float* p = attQ + (size_t)b * 8 * 4096 + e;
    float s = 0.f;
    #pragma unroll
    for (int q = 0; q < 8; ++q) s += p[(size_t)q * 4096];
    att_s[e] = s;
  }
  __syncthreads();
  for (int idx = tid; idx < 8192; idx += 1024) {
    const int h = idx >> 12, o = (idx >> 6) & 63, d = idx & 63;
    float s = 0.f;
    #pragma unroll
    for (int i = 0; i < 32; ++i)
      s = __builtin_fmaf(wms[o][i], att_s[(2 * i + h) * 64 + d], s);
    Mp[h][o][d] = s;
  }
  __syncthreads();
  const float scale = 1.f / (sums[b] * sums[8 + b]);
  for (int idx = tid; idx < 16384; idx += 1024) {
    const int oo = idx >> 7, cc = idx & 127;
    const int h = oo >> 6, o = oo & 63, e = cc >> 6, c = cc & 63;
    float s = 0.f;
    #pragma unroll
    for (int j = 0; j < 32; ++j)
      s = __builtin_fmaf(Mp[h][o][2 * j + e], wts[j][c], s);
    s *= scale;
    const unsigned short hi = f2bf(s);
    Nhi[(size_t)b * 16384 + idx] = hi;
    Nlo[(size_t)b * 16384 + idx] = f2bf(s - bf2f(hi));
  }
}

// ---------------------------------------------------------------------------
// k5: out[b][o][h*NPOS+n] = sum_cc N[b][h*64+o][cc] * x[b][cc&63][(cc>>6)*NPOS+n]
// A = x [n][cc], B = N rows (oo) -> lane stores float4 of consecutive n.
// Staging: scalar dword loads (lanes span n) -> 16 contiguous cc per thread
// -> 2x ds_write_b128. Grid (512, 8), LDS 16 KB, (512,3) bounds.
// ---------------------------------------------------------------------------
__global__ __launch_bounds__(512, 3) void k5_out(
    const float* __restrict__ x, const unsigned short* __restrict__ Nhi,
    const unsigned short* __restrict__ Nlo, float* __restrict__ out)
{
  __shared__ unsigned short Xh[64 * 128];   // [n][cc] bf16, cc ^ (slot4(n)<<3)
  const int tid = threadIdx.x;
  const int b = blockIdx.y, n0 = blockIdx.x * 64;
  const int w = tid >> 6, l = tid & 63;
  const int lr = l & 15, g = l >> 4;

  // B-fragments: N rows oo = w*16 + lr, K=128 (4 ksteps), hi/lo
  short8 bh[4], bl[4];
  #pragma unroll
  for (int ks = 0; ks < 4; ++ks) {
    const size_t off = (size_t)b * 16384 + (size_t)(w * 16 + lr) * 128 + ks * 32 + g * 8;
    bh[ks] = *(const short8*)(Nhi + off);
    bl[ks] = *(const short8*)(Nlo + off);
  }

  // stage X tile [n][cc]: wave w owns cc in [w*16, w*16+16); lane spans n
  {
    const int ccb = w * 16;
    const int c0 = ccb & 63, e0 = ccb >> 6;
    const float* xp = x + (size_t)b * 64 * HW + (size_t)c0 * HW
                    + (size_t)e0 * NPOS + n0 + l;
    float v[16];
    #pragma unroll
    for (int i = 0; i < 16; ++i) v[i] = xp[(size_t)i * HW];
    short8 pa, pb;
    #pragma unroll
    for (int i = 0; i < 8; ++i) {
      pa[i] = (short)f2bf(v[i]);
      pb[i] = (short)f2bf(v[8 + i]);
    }
    const int s8 = slot4(l) << 3;
    *(short8*)&Xh[l * 128 + (ccb ^ s8)] = pa;
    *(short8*)&Xh[l * 128 + ((ccb + 8) ^ s8)] = pb;
  }
  __syncthreads();

  const int oo = w * 16 + lr;   // this lane's output row (D col = lr)
  float* op = out + (size_t)b * 64 * HW + (size_t)(oo & 63) * HW
            + (size_t)(oo >> 6) * NPOS + n0 + g * 4;

  #pragma unroll
  for (int ct4 = 0; ct4 < 4; ++ct4) {
    f32x4 acc = {0.f, 0.f, 0.f, 0.f};
    const int arow = ct4 * 16 + lr;
    const int sw = slot4(arow) << 3;
    #pragma unroll
    for (int ks = 0; ks < 4; ++ks) {
      const short8 av = *(const short8*)&Xh[arow * 128 + ((ks * 32 + g * 8) ^ sw)];
      acc = __builtin_amdgcn_mfma_f32_16x16x32_bf16(av, bh[ks], acc, 0, 0, 0);
      acc = __builtin_amdgcn_mfma_f32_16x16x32_bf16(av, bl[ks], acc, 0, 0, 0);
    }
    // D: row (n within subtile) = g*4 + r, col = lr -> float4 store
    *(float4*)(op + ct4 * 16) = *(float4*)&acc;
  }
}

// ---------------------------------------------------------------------------
extern "C" void kernel_launch(void* const* d_in, const int* in_sizes, int n_in,
                              void* d_out, int out_size, void* d_ws, size_t ws_size,
                              hipStream_t stream)
{
  const float* x      = (const float*)d_in[0];
  const float* wphi   = (const float*)d_in[1];
  const float* wtheta = (const float*)d_in[2];
  const float* wg     = (const float*)d_in[3];
  const float* wm     = (const float*)d_in[4];
  float* out = (float*)d_out;

  char* ws = (char*)d_ws;
  float* attP         = (float*)ws;                                 // 16,777,216 B
  unsigned short* Whi = (unsigned short*)(ws + 16777216);           //      8,192 B
  unsigned short* Wlo = (unsigned short*)(ws + 16785408);           //      8,192 B
  unsigned short* Nhi = (unsigned short*)(ws + 16793600);           //    262,144 B
  unsigned short* Nlo = (unsigned short*)(ws + 17055744);           //    262,144 B
  float* sums         = (float*)(ws + 17317888);                    //         64 B
  float* attQ         = (float*)(ws + 17317952);                    //  1,048,576 B

  hipMemsetAsync(sums, 0, 64, stream);
  k0_prep<<<dim3(16), 256, 0, stream>>>(wphi, wg, Whi, Wlo);
  k1_att<<<dim3(128, 8), 512, 0, stream>>>(x, Whi, Wlo, attP, sums);
  k3a_reduce<<<dim3(64), 256, 0, stream>>>(attP, attQ);
  k3b_nmat<<<dim3(8), 1024, 0, stream>>>(attQ, sums, wm, wtheta, Nhi, Nlo);
  k5_out<<<dim3(512, 8), 512, 0, stream>>>(x, Nhi, Nlo, out);
}